// Round 18
// baseline (478.070 us; speedup 1.0000x reference)
//
#include <hip/hip_runtime.h>
#include <math.h>

// R16 (473us, best) + act-register double-buffer, with CORRECT pipeline
// ordering (R17 bug: w2 was overwritten at loop top before its chunk was
// consumed -> chunk c+2 skipped; fix = load w2 AFTER rotation, like R16).
// gemvP<NR,CH>: block = 256 thr = 4 waves, owns 4 consecutive W rows; wave qt
// covers act rows I0..I0+4 (I0 = min(4*qt, NR-5); boundary rows duplicated,
// bitwise-identical double-writes). Slab = CH*256 cols. Weights 2 chunks in
// flight (w0/w1/w2 rotation), acts 1 chunk ahead (an). Live VGPR ~= 118 <=
// 128 cap of launch_bounds(256,4) (R14-16 proven; WRITE_SIZE = spill alarm).
// S k-split planes; consumers (attn/gelu/redln) sum planes.

__global__ void k0_init(const float* __restrict__ x,
                        const float* __restrict__ bias,
                        const float* __restrict__ cls,
                        float* __restrict__ ss,
                        float* __restrict__ altx) {
    int idx = blockIdx.x * 256 + threadIdx.x;
    if (idx < 17 * 2048) {
        int r = idx >> 11, m = idx & 2047;
        float v = bias[idx];
        if (r == 0) v += cls[m];
        ss[idx] = v;
    }
    if (idx < 16 * 2048) {
        int i = idx >> 11, m = idx & 2047;
        int c1 = m >> 6, c2 = m & 63;
        const float* p = x + (size_t)(c2 * 32 + c1) * 160 + i * 10;
        float s = 0.f;
#pragma unroll
        for (int j = 0; j < 10; ++j) s += p[j];
        altx[idx] = s * 0.1f;
    }
}

// grid (L/4, S); slab = CH*256; out[i,l] = sum_m act[i,m]*W[l,m]
template <int NR, int CH>
__global__ __launch_bounds__(256, 4) void gemvP(
    const float* __restrict__ W, const float* __restrict__ act,
    float* __restrict__ P, int L, int K) {
    const int lane = threadIdx.x & 63;
    const int qt = threadIdx.x >> 6;
    const int I0 = (qt * 4 < NR - 5) ? qt * 4 : NR - 5;
    const int l0 = blockIdx.x * 4;
    const int k0 = blockIdx.y * (CH * 256);
    const float* Wp = W + (size_t)l0 * K + k0 + lane * 4;
    const float* Ap = act + (size_t)I0 * K + k0 + lane * 4;

    float acc[5][4];
#pragma unroll
    for (int j = 0; j < 5; ++j)
#pragma unroll
        for (int r = 0; r < 4; ++r) acc[j][r] = 0.f;

    float4 w0[4], w1[4], w2[4], a4[5], an[5];
#pragma unroll
    for (int r = 0; r < 4; ++r)
        w0[r] = *reinterpret_cast<const float4*>(Wp + (size_t)r * K);
#pragma unroll
    for (int r = 0; r < 4; ++r)
        w1[r] = *reinterpret_cast<const float4*>(Wp + (size_t)r * K + 256);
#pragma unroll
    for (int r = 0; r < 4; ++r)
        w2[r] = *reinterpret_cast<const float4*>(Wp + (size_t)r * K + 512);
#pragma unroll
    for (int j = 0; j < 5; ++j)
        a4[j] = *reinterpret_cast<const float4*>(Ap + (size_t)j * K);

#pragma unroll
    for (int c = 0; c < CH; ++c) {
        // issue next-chunk act loads (1 ahead; 'an' clobbers nothing live)
        if (c + 1 < CH) {
#pragma unroll
            for (int j = 0; j < 5; ++j)
                an[j] = *reinterpret_cast<const float4*>(
                    Ap + (size_t)j * K + (c + 1) * 256);
        }
        // FMA on current regs (loaded >=1 chunk ago)
#pragma unroll
        for (int j = 0; j < 5; ++j)
#pragma unroll
            for (int r = 0; r < 4; ++r)
                acc[j][r] += a4[j].x * w0[r].x + a4[j].y * w0[r].y +
                             a4[j].z * w0[r].z + a4[j].w * w0[r].w;
        // rotate THEN refill w2 (R16 ordering: w2's old chunk was just
        // copied to w1, so the refill clobbers nothing live)
#pragma unroll
        for (int r = 0; r < 4; ++r) w0[r] = w1[r];
#pragma unroll
        for (int r = 0; r < 4; ++r) w1[r] = w2[r];
        if (c + 3 < CH) {
#pragma unroll
            for (int r = 0; r < 4; ++r)
                w2[r] = *reinterpret_cast<const float4*>(
                    Wp + (size_t)r * K + (c + 3) * 256);
        }
#pragma unroll
        for (int j = 0; j < 5; ++j) a4[j] = an[j];
    }

    // butterfly k-reduce; lane j*4+r keeps output (I0+j, l0+r)
    float vout = 0.f;
#pragma unroll
    for (int j = 0; j < 5; ++j)
#pragma unroll
        for (int r = 0; r < 4; ++r) {
            float v = acc[j][r];
#pragma unroll
            for (int off = 32; off; off >>= 1) v += __shfl_xor(v, off);
            if (lane == j * 4 + r) vout = v;
        }
    if (lane < 20)
        P[(size_t)blockIdx.y * NR * L + (size_t)(I0 + (lane >> 2)) * L +
          l0 + (lane & 3)] = vout;
}

// tbuf = gelu(Pf + fc1_b)
__global__ void red_gelu(const float* __restrict__ Pf, const float* __restrict__ fb,
                         float* __restrict__ out) {
    int idx = blockIdx.x * 256 + threadIdx.x;
    float s = fb[idx & 8191] + Pf[idx];
    out[idx] = 0.5f * s * (1.f + erff(s * 0.70710678f));
}

// one block per row: ss[row] += sum_S P[row] (+fb); lnout = LN(ss)*g+b
__global__ void redln(const float* __restrict__ P, int S, int rowoff, int NRL,
                      const float* __restrict__ fb, float* __restrict__ ss,
                      const float* __restrict__ g, const float* __restrict__ b,
                      float* __restrict__ lnout) {
    const int row = blockIdx.x;
    const int tid = threadIdx.x;
    const int base = row * 2048;
    float vv[8];
    float s = 0.f, q = 0.f;
#pragma unroll
    for (int c = 0; c < 8; ++c) {
        int col = tid + c * 256;
        float xv = ss[base + col];
        if (row >= rowoff) {
            const float* pp = P + (size_t)(row - rowoff) * 2048 + col;
            for (int y = 0; y < S; ++y) xv += pp[(size_t)y * NRL];
        }
        if (fb != nullptr) xv += fb[col];
        ss[base + col] = xv;
        vv[c] = xv;
        s += xv;
        q += xv * xv;
    }
#pragma unroll
    for (int off = 32; off; off >>= 1) {
        s += __shfl_xor(s, off);
        q += __shfl_xor(q, off);
    }
    __shared__ float red[8];
    int wvi = tid >> 6;
    if ((tid & 63) == 0) { red[wvi] = s; red[4 + wvi] = q; }
    __syncthreads();
    s = red[0] + red[1] + red[2] + red[3];
    q = red[4] + red[5] + red[6] + red[7];
    float mean = s * (1.f / 2048.f);
    float var = q * (1.f / 2048.f) - mean * mean;
    float rstd = rsqrtf(var + 1e-5f);
#pragma unroll
    for (int c = 0; c < 8; ++c) {
        int col = tid + c * 256;
        lnout[base + col] = (vv[c] - mean) * rstd * g[col] + b[col];
    }
}

// one block per head; 64 threads; reads qkv directly
__global__ void attn_kernel(const float* __restrict__ qkv, float* __restrict__ imv) {
    int h = blockIdx.x, lane = threadIdx.x;
    const float scale = 0.08838834764831845f;  // 1/sqrt(128)
    float run0 = 0.f, run1 = 0.f;
    for (int i = 0; i < 17; ++i) {
        const float* base = qkv + (size_t)i * 6144 + h * 128;
        float q0 = base[lane], q1 = base[lane + 64];
        float k0 = base[2048 + lane], k1 = base[2048 + lane + 64];
        float v0 = base[4096 + lane], v1 = base[4096 + lane + 64];
        float p = q0 * k0 + q1 * k1;
#pragma unroll
        for (int off = 32; off; off >>= 1) p += __shfl_xor(p, off);
        float rsa = p * scale;
        float iv0 = rsa * v0, iv1 = rsa * v1;
        float o0, o1;
        if (i < 16) { run0 += iv0; run1 += iv1; o0 = run0; o1 = run1; }
        else        { o0 = iv0; o1 = iv1; }
        imv[(size_t)i * 2048 + h * 128 + lane] = o0;
        imv[(size_t)i * 2048 + h * 128 + lane + 64] = o1;
    }
}

extern "C" void kernel_launch(void* const* d_in, const int* in_sizes, int n_in,
                              void* d_out, int out_size, void* d_ws, size_t ws_size,
                              hipStream_t stream) {
    const float* x      = (const float*)d_in[0];
    const float* weight = (const float*)d_in[1];
    const float* bias   = (const float*)d_in[2];
    const float* cls    = (const float*)d_in[3];
    const float* Wqkv   = (const float*)d_in[4];
    const float* Wo     = (const float*)d_in[5];
    const float* ln1_g  = (const float*)d_in[6];
    const float* ln1_b  = (const float*)d_in[7];
    const float* ln2_g  = (const float*)d_in[8];
    const float* ln2_b  = (const float*)d_in[9];
    const float* ln3_g  = (const float*)d_in[10];
    const float* ln3_b  = (const float*)d_in[11];
    const float* fc1_w  = (const float*)d_in[12];
    const float* fc1_b  = (const float*)d_in[13];
    const float* fc2_w  = (const float*)d_in[14];
    const float* fc2_b  = (const float*)d_in[15];
    float* out = (float*)d_out;

    float* ws     = (float*)d_ws;
    float* ss     = ws;                  // 34816
    float* altx   = ws + 34816;          // 32768
    float* imv    = ws + 67584;          // 34816
    float* qkv    = ws + 102400;         // 104448
    float* Pf     = ws + 206848;         // 139264 (fc1 raw)
    float* tbuf   = ws + 346112;         // 139264 (gelu out)
    float* ln1buf = ws + 485376;         // 34816
    float* ln2buf = ws + 520192;         // 34816
    float* Pg     = ws + 555008;         // 139264 (k-split planes)

    k0_init<<<136, 256, 0, stream>>>(x, bias, cls, ss, altx);
    // ss[1:17] += altx @ weight.T  (2 planes [16][2048], CH=4)
    gemvP<16, 4><<<dim3(512, 2), 256, 0, stream>>>(weight, altx, Pg, 2048, 2048);
    redln<<<17, 256, 0, stream>>>(Pg, 2, 1, 32768, nullptr, ss, ln1_g, ln1_b, ln1buf);

    for (int k = 0; k < 4; ++k) {
        // qkv = Wqkv[k] @ ln1buf  (direct, L=6144, CH=8)
        gemvP<17, 8><<<dim3(1536, 1), 256, 0, stream>>>(
            Wqkv + (size_t)k * 12582912, ln1buf, qkv, 6144, 2048);
        attn_kernel<<<16, 64, 0, stream>>>(qkv, imv);
        // Pg = imv @ Wo[k].T  (2 planes [17][2048], CH=4)
        gemvP<17, 4><<<dim3(512, 2), 256, 0, stream>>>(
            Wo + (size_t)k * 4194304, imv, Pg, 2048, 2048);
        redln<<<17, 256, 0, stream>>>(Pg, 2, 0, 34816, nullptr, ss, ln2_g, ln2_b, ln2buf);
        // Pf = fc1_w @ ln2buf  (direct raw, L=8192, CH=8)
        gemvP<17, 8><<<dim3(2048, 1), 256, 0, stream>>>(fc1_w, ln2buf, Pf, 8192, 2048);
        red_gelu<<<544, 256, 0, stream>>>(Pf, fc1_b, tbuf);
        // Pg = fc2_w @ tbuf  (4 planes [17][2048], K=8192, CH=8)
        gemvP<17, 8><<<dim3(512, 4), 256, 0, stream>>>(fc2_w, tbuf, Pg, 2048, 8192);
        if (k < 3)
            redln<<<17, 256, 0, stream>>>(Pg, 4, 0, 34816, fc2_b, ss, ln1_g, ln1_b, ln1buf);
        else
            redln<<<17, 256, 0, stream>>>(Pg, 4, 0, 34816, fc2_b, ss, ln3_g, ln3_b, out);
    }
}